// Round 8
// baseline (8043.893 us; speedup 1.0000x reference)
//
#include <hip/hip_runtime.h>

typedef unsigned short u16;

#define DIMSZ 1024
#define HEADS 16
#define BLKSZ 129
#define NBLK 32
#define NTOK (BLKSZ * NBLK)      // 4128
#define BATCH 4
#define MROWS (BATCH * NTOK)     // 16512

__device__ __forceinline__ float bf2f(u16 u) {
  return __uint_as_float(((unsigned)u) << 16);
}
__device__ __forceinline__ u16 f2bf(float f) {
  unsigned u = __float_as_uint(f);
  u += 0x7FFFu + ((u >> 16) & 1u);   // round-to-nearest-even
  return (u16)(u >> 16);
}

// ---------------------------------------------------------------------------
// PURE-VALU GEMM. C[m][n] = sum_k A[m][k] * B[n][k] (+ bias[n]).
// A/B f32 or bf16 per flags; OF32 selects f32 vs bf16 output.
// Tile: 16(m) x 64(n), BK=64, 256 threads, 4 outputs/thread. LDS stride 65.
// ---------------------------------------------------------------------------
template<bool AF32, bool BF32, bool OF32>
__global__ __launch_bounds__(256) void gemm_bt_valu(
    const void* __restrict__ Av, const void* __restrict__ Bv,
    void* __restrict__ Cv, const float* __restrict__ bias,
    int M, int N, int K)
{
  __shared__ float sA[16 * 65];
  __shared__ float sB[64 * 65];
  const int tid = threadIdx.x;
  const int ty = tid >> 4;        // 0..15 : m within tile
  const int tx = tid & 15;        // 0..15 : n group (4 cols each)
  const int m0 = blockIdx.x * 16;
  const int n0 = blockIdx.y * 64;

  float acc0 = 0.f, acc1 = 0.f, acc2 = 0.f, acc3 = 0.f;

  for (int k0 = 0; k0 < K; k0 += 64) {
    for (int i = tid; i < 16 * 64; i += 256) {
      int r = i >> 6, c = i & 63;
      sA[r * 65 + c] = AF32
          ? ((const float*)Av)[(size_t)(m0 + r) * K + k0 + c]
          : bf2f(((const u16*)Av)[(size_t)(m0 + r) * K + k0 + c]);
    }
    for (int i = tid; i < 64 * 64; i += 256) {
      int r = i >> 6, c = i & 63;
      sB[r * 65 + c] = BF32
          ? ((const float*)Bv)[(size_t)(n0 + r) * K + k0 + c]
          : bf2f(((const u16*)Bv)[(size_t)(n0 + r) * K + k0 + c]);
    }
    __syncthreads();

    for (int k = 0; k < 64; ++k) {
      float a = sA[ty * 65 + k];
      acc0 += a * sB[(tx * 4 + 0) * 65 + k];
      acc1 += a * sB[(tx * 4 + 1) * 65 + k];
      acc2 += a * sB[(tx * 4 + 2) * 65 + k];
      acc3 += a * sB[(tx * 4 + 3) * 65 + k];
    }
    __syncthreads();
  }

  float r4[4] = {acc0, acc1, acc2, acc3};
#pragma unroll
  for (int i = 0; i < 4; ++i) {
    int col = n0 + tx * 4 + i;
    float bv = bias ? bias[col] : 0.f;
    if (OF32)
      ((float*)Cv)[(size_t)(m0 + ty) * N + col] = r4[i] + bv;
    else
      ((u16*)Cv)[(size_t)(m0 + ty) * N + col] = f2bf(r4[i] + bv);
  }
}

// ---------------------------------------------------------------------------
// Global attention among the 32 block-leader tokens, per (b,h). One wave/WG.
// Lanes >=32 masked out of score/sum (32 keys only). g[b][blk][h][dv] f32.
// ---------------------------------------------------------------------------
__global__ __launch_bounds__(64) void global_attn(
    const u16* __restrict__ q, const u16* __restrict__ k,
    const u16* __restrict__ v, float* __restrict__ g)
{
  __shared__ float sQ[NBLK * 64];
  __shared__ float sKT[64 * NBLK];   // transposed [d][j]
  __shared__ float sV[NBLK * 64];
  __shared__ float sp[NBLK];
  const int b = blockIdx.x >> 4, h = blockIdx.x & 15;
  const int lane = threadIdx.x;

  for (int idx = lane; idx < NBLK * 64; idx += 64) {
    int j = idx >> 6, d = idx & 63;
    size_t off = ((size_t)(b * NTOK + j * BLKSZ)) * DIMSZ + h * 64 + d;
    sQ[idx] = bf2f(q[off]);
    sKT[d * NBLK + j] = bf2f(k[off]);
    sV[idx] = bf2f(v[off]);
  }
  __syncthreads();

  for (int i = 0; i < NBLK; ++i) {
    float s = -3.0e38f;
    if (lane < 32) {
      float acc = 0.f;
      for (int d = 0; d < 64; ++d) acc += sQ[i * 64 + d] * sKT[d * NBLK + lane];
      s = acc * 0.125f;
    }
    float m = s;
    for (int t = 1; t < 64; t <<= 1) m = fmaxf(m, __shfl_xor(m, t));
    float e = (lane < 32) ? __expf(s - m) : 0.f;
    float sum = e;
    for (int t = 1; t < 64; t <<= 1) sum += __shfl_xor(sum, t);
    if (lane < 32) sp[lane] = e / sum;
    __syncthreads();
    float acc = 0.f;
    for (int jj = 0; jj < NBLK; ++jj) acc += sp[jj] * sV[jj * 64 + lane];
    g[(((size_t)b * NBLK + i) * HEADS + h) * 64 + lane] = acc;
    __syncthreads();
  }
}

// ---------------------------------------------------------------------------
// SIMPLE block-local attention (pure VALU, f32 softmax/PV).
// One WG (256 thr) per (b, blk, h); wave w handles rows w, w+4, ...
// Writes ao IN PLACE over q (disjoint slices across WGs; within a WG all q
// reads land in LDS before the barrier preceding any ao store).
// ---------------------------------------------------------------------------
__global__ __launch_bounds__(256) void block_attn_simple(
    const u16* q, const u16* __restrict__ k,
    const u16* __restrict__ v, const float* __restrict__ g,
    u16* ao)
{
  __shared__ u16 sQ[BLKSZ * 64];      // [row][d]
  __shared__ u16 sKT[64 * 132];       // [d][key] padded
  __shared__ u16 sV[BLKSZ * 64];      // [key][dv]
  __shared__ float sP[4][132];        // per-wave P row
  const int b = blockIdx.x, blk = blockIdx.y, h = blockIdx.z;
  const int tid = threadIdx.x, lane = tid & 63, w = tid >> 6;
  const int h64 = h * 64;
  const size_t row_base = (size_t)b * NTOK + (size_t)blk * BLKSZ;

  for (int idx = tid; idx < BLKSZ * 64; idx += 256) {
    int r = idx >> 6, d = idx & 63;
    size_t off = (row_base + r) * DIMSZ + h64 + d;
    sQ[idx] = q[off];
    sKT[d * 132 + r] = k[off];
    sV[idx] = v[off];
  }
  __syncthreads();

  for (int row = w; row < BLKSZ; row += 4) {
    float s0 = 0.f, s1 = 0.f, s2 = 0.f;
    for (int d = 0; d < 64; ++d) {
      float qd = bf2f(sQ[row * 64 + d]);
      s0 += qd * bf2f(sKT[d * 132 + lane]);
      s1 += qd * bf2f(sKT[d * 132 + 64 + lane]);
      s2 += qd * bf2f(sKT[d * 132 + 128]);   // broadcast (key 128)
    }
    s0 *= 0.125f; s1 *= 0.125f; s2 *= 0.125f;
    float m = fmaxf(fmaxf(s0, s1), s2);
    for (int t = 1; t < 64; t <<= 1) m = fmaxf(m, __shfl_xor(m, t));
    float e0 = __expf(s0 - m), e1 = __expf(s1 - m), e2 = __expf(s2 - m);
    float sum = e0 + e1 + (lane == 0 ? e2 : 0.f);
    for (int t = 1; t < 64; t <<= 1) sum += __shfl_xor(sum, t);
    float inv = 1.f / sum;
    sP[w][lane] = e0 * inv;
    sP[w][64 + lane] = e1 * inv;
    if (lane == 0) sP[w][128] = e2 * inv;
    __builtin_amdgcn_s_waitcnt(0);           // wave-private LDS write->read
    float acc = 0.f;
    for (int j = 0; j < BLKSZ; ++j)
      acc += sP[w][j] * bf2f(sV[j * 64 + lane]);
    if (row == 0)
      acc += g[(((size_t)b * NBLK + blk) * HEADS + h) * 64 + lane];
    ao[(row_base + row) * DIMSZ + h64 + lane] = f2bf(acc);
  }
}

// ---------------------------------------------------------------------------
extern "C" void kernel_launch(void* const* d_in, const int* in_sizes, int n_in,
                              void* d_out, int out_size, void* d_ws, size_t ws_size,
                              hipStream_t stream) {
  // Inputs are FLOAT32; output is FLOAT32 (reference returns f32 — the
  // rounds-4..7 constant absmax=2.125 matched the signature of bf16 codes
  // read back as f32 words exactly).
  const float* x  = (const float*)d_in[0];
  const float* Wq = (const float*)d_in[1];
  const float* Wk = (const float*)d_in[2];
  const float* Wv = (const float*)d_in[3];
  const float* Wo = (const float*)d_in[4];
  const float* bo = (const float*)d_in[5];
  float* out = (float*)d_out;

  // Scratch layout:
  //   d_out (16.9M f32 = 67.6 MB) during attention phase:
  //     [0, 33.8MB)    v  (u16 bf16)
  //     [33.8, 67.6MB) k  (u16 bf16)
  //   (final GEMM overwrites all of d_out with f32 afterwards, stream-ordered)
  //   d_ws (34.8 MB used):
  //     [0, 1MB)       g  (f32, 512 KB used)
  //     [1MB, +33.8MB) qb (u16 bf16), overwritten in place by attention out
  char* ws = (char*)d_ws;
  float* gb = (float*)ws;
  u16*   qb = (u16*)(ws + (1u << 20));
  u16*   vb = (u16*)d_out;
  u16*   kb = (u16*)d_out + (size_t)MROWS * DIMSZ;

  dim3 vgrid(MROWS / 16, DIMSZ / 64);   // (1032, 16)
  gemm_bt_valu<true, true, false><<<vgrid, 256, 0, stream>>>(x, Wq, qb, nullptr, MROWS, DIMSZ, DIMSZ);
  gemm_bt_valu<true, true, false><<<vgrid, 256, 0, stream>>>(x, Wk, kb, nullptr, MROWS, DIMSZ, DIMSZ);
  gemm_bt_valu<true, true, false><<<vgrid, 256, 0, stream>>>(x, Wv, vb, nullptr, MROWS, DIMSZ, DIMSZ);
  global_attn<<<dim3(BATCH * HEADS), 64, 0, stream>>>(qb, kb, vb, gb);
  block_attn_simple<<<dim3(BATCH, NBLK, HEADS), 256, 0, stream>>>(qb, kb, vb, gb, qb);
  gemm_bt_valu<false, true, true><<<vgrid, 256, 0, stream>>>(qb, Wo, out, bo, MROWS, DIMSZ, DIMSZ);
}

// Round 9
// 712.938 us; speedup vs baseline: 11.2827x; 11.2827x over previous
//
#include <hip/hip_runtime.h>

typedef unsigned short u16;
typedef __attribute__((ext_vector_type(8))) __bf16 bf16x8;
typedef __attribute__((ext_vector_type(4))) float f32x4;
typedef __attribute__((ext_vector_type(8))) u16 u16x8;
typedef __attribute__((ext_vector_type(4))) u16 u16x4;

#define DIMSZ 1024
#define HEADS 16
#define BLKSZ 129
#define NBLK 32
#define NTOK (BLKSZ * NBLK)      // 4128
#define BATCH 4
#define MROWS (BATCH * NTOK)     // 16512

#define MFMA __builtin_amdgcn_mfma_f32_16x16x32_bf16

__device__ __forceinline__ float bf2f(u16 u) {
  return __uint_as_float(((unsigned)u) << 16);
}
__device__ __forceinline__ u16 f2bf(float f) {
  unsigned u = __float_as_uint(f);
  u += 0x7FFFu + ((u >> 16) & 1u);   // round-to-nearest-even
  return (u16)(u >> 16);
}

// async global->LDS, 16B/lane; LDS dest = wave-uniform base + lane*16 (m97)
#define GLD16(ldsp, gp) __builtin_amdgcn_global_load_lds( \
    (const __attribute__((address_space(1))) void*)(gp),   \
    (__attribute__((address_space(3))) void*)(ldsp), 16, 0, 0)

// ---------------------------------------------------------------------------
// f32 -> bf16 cast, 4 elems/thread.
// ---------------------------------------------------------------------------
__global__ __launch_bounds__(256) void cast_f32_bf16(
    const float* __restrict__ in, u16* __restrict__ out, int n)
{
  int i = (blockIdx.x * 256 + threadIdx.x) * 4;
  if (i < n) {
    float4 f = *(const float4*)(in + i);
    u16x4 o = { f2bf(f.x), f2bf(f.y), f2bf(f.z), f2bf(f.w) };
    *(u16x4*)(out + i) = o;
  }
}

// Stage one 128x64 tile into LDS as bf16. bf16 source: global_load_lds x16
// (async; caller must s_waitcnt). f32 source: vector load + convert.
template<bool F32>
__device__ __forceinline__ void stage(u16* dst, const void* src,
                                      int row0, int K, int k0, int tid) {
  if (F32) {
    const float* s = (const float*)src;
#pragma unroll
    for (int i = 0; i < 8; ++i) {
      int slot = i * 256 + tid;          // 2048 slots x 4 f32
      int row = slot >> 4, cc = (slot & 15) * 4;
      float4 f = *(const float4*)(s + (size_t)(row0 + row) * K + k0 + cc);
      u16x4 o = { f2bf(f.x), f2bf(f.y), f2bf(f.z), f2bf(f.w) };
      *(u16x4*)(dst + row * 64 + cc) = o;
    }
  } else {
    const u16* s = (const u16*)src;
#pragma unroll
    for (int i = 0; i < 4; ++i) {
      int off = i * 4096 + tid * 16;     // byte offset in 16 KB tile
      int row = off >> 7;                // 128 B per row (64 bf16)
      int col = (off & 127) >> 1;
      GLD16((char*)dst + off, s + (size_t)(row0 + row) * K + k0 + col);
    }
  }
}

// ---------------------------------------------------------------------------
// C[m][n] = sum_k A[m][k]*B[n][k] (+bias[n]); bf16 MFMA core (m97 structure:
// 128x128 tile, BK=64, 4 waves x 4x4 acc). OF32 picks f32 vs bf16 C.
// ---------------------------------------------------------------------------
template<bool AF32, bool BF32, bool OF32>
__global__ __launch_bounds__(256) void gemm_bt(
    const void* __restrict__ A, const void* __restrict__ B,
    void* __restrict__ C, const float* __restrict__ bias,
    int M, int N, int K)
{
  __shared__ u16 sA[128 * 64];   // 16 KB
  __shared__ u16 sB[128 * 64];   // 16 KB
  const int tid  = threadIdx.x;
  const int lane = tid & 63;
  const int wid  = tid >> 6;
  const int qd   = lane >> 4;
  const int l15  = lane & 15;
  const int m0 = blockIdx.x * 128;
  const int n0 = blockIdx.y * 128;
  const int wm = (wid >> 1) * 64;
  const int wn = (wid & 1) * 64;

  const f32x4 zero4 = {0.f, 0.f, 0.f, 0.f};
  f32x4 acc[4][4];
  for (int mi = 0; mi < 4; ++mi)
    for (int ni = 0; ni < 4; ++ni)
      acc[mi][ni] = zero4;

  for (int k0 = 0; k0 < K; k0 += 64) {
    stage<AF32>(sA, A, m0, K, k0, tid);
    stage<BF32>(sB, B, n0, K, k0, tid);
    if (!AF32 || !BF32) __builtin_amdgcn_s_waitcnt(0);   // drain global_load_lds
    __syncthreads();

#pragma unroll
    for (int kk = 0; kk < 64; kk += 32) {
      bf16x8 af[4], bv[4];
#pragma unroll
      for (int mi = 0; mi < 4; ++mi)
        af[mi] = *(const bf16x8*)&sA[(wm + mi * 16 + l15) * 64 + kk + qd * 8];
#pragma unroll
      for (int ni = 0; ni < 4; ++ni)
        bv[ni] = *(const bf16x8*)&sB[(wn + ni * 16 + l15) * 64 + kk + qd * 8];
#pragma unroll
      for (int mi = 0; mi < 4; ++mi)
#pragma unroll
        for (int ni = 0; ni < 4; ++ni)
          acc[mi][ni] = MFMA(af[mi], bv[ni], acc[mi][ni], 0, 0, 0);
    }
    __syncthreads();
  }

#pragma unroll
  for (int mi = 0; mi < 4; ++mi) {
#pragma unroll
    for (int ni = 0; ni < 4; ++ni) {
      int row0 = m0 + wm + mi * 16 + qd * 4;
      int col  = n0 + wn + ni * 16 + l15;
      float badd = bias ? bias[col] : 0.0f;
#pragma unroll
      for (int r = 0; r < 4; ++r) {
        float v = acc[mi][ni][r] + badd;
        if (OF32) ((float*)C)[(size_t)(row0 + r) * N + col] = v;
        else      ((u16*)C)[(size_t)(row0 + r) * N + col] = f2bf(v);
      }
    }
  }
}

// ---------------------------------------------------------------------------
// Global attention among the 32 block-leader tokens, per (b,h). One wave/WG.
// ---------------------------------------------------------------------------
__global__ __launch_bounds__(64) void global_attn(
    const u16* __restrict__ q, const u16* __restrict__ k,
    const u16* __restrict__ v, float* __restrict__ g)
{
  __shared__ float sQ[NBLK * 64];
  __shared__ float sKT[64 * NBLK];
  __shared__ float sV[NBLK * 64];
  __shared__ float sp[NBLK];
  const int b = blockIdx.x >> 4, h = blockIdx.x & 15;
  const int lane = threadIdx.x;

  for (int idx = lane; idx < NBLK * 64; idx += 64) {
    int j = idx >> 6, d = idx & 63;
    size_t off = ((size_t)(b * NTOK + j * BLKSZ)) * DIMSZ + h * 64 + d;
    sQ[idx] = bf2f(q[off]);
    sKT[d * NBLK + j] = bf2f(k[off]);
    sV[idx] = bf2f(v[off]);
  }
  __syncthreads();

  for (int i = 0; i < NBLK; ++i) {
    float s = -3.0e38f;
    if (lane < 32) {
      float acc = 0.f;
      for (int d = 0; d < 64; ++d) acc += sQ[i * 64 + d] * sKT[d * NBLK + lane];
      s = acc * 0.125f;
    }
    float m = s;
    for (int t = 1; t < 64; t <<= 1) m = fmaxf(m, __shfl_xor(m, t));
    float e = (lane < 32) ? __expf(s - m) : 0.f;
    float sum = e;
    for (int t = 1; t < 64; t <<= 1) sum += __shfl_xor(sum, t);
    if (lane < 32) sp[lane] = e / sum;
    __syncthreads();
    float acc = 0.f;
    for (int jj = 0; jj < NBLK; ++jj) acc += sp[jj] * sV[jj * 64 + lane];
    g[(((size_t)b * NBLK + i) * HEADS + h) * 64 + lane] = acc;
    __syncthreads();
  }
}

// ---------------------------------------------------------------------------
// MFMA block-local attention (equivalence-proven vs VALU in rounds 5-7).
// One WG per (b, blk, h). Pads to 144; PV keys 0..127 MFMA + rank-1 key 128.
// Writes ao IN PLACE over q (disjoint WG slices; q reads done pre-barrier).
// ---------------------------------------------------------------------------
__global__ __launch_bounds__(256) void block_attn(
    const u16* q, const u16* __restrict__ k,
    const u16* __restrict__ v, const float* __restrict__ g,
    u16* ao)
{
  __shared__ u16 sS[144 * 144];     // scores then P (bf16), stride 144
  __shared__ u16 sKV[144 * 64];     // phase1: K [key][d]; phase3: V^T [dv][key]
  const int b = blockIdx.x, blk = blockIdx.y, h = blockIdx.z;
  const int tid = threadIdx.x, lane = tid & 63, w = tid >> 6;
  const int qd = lane >> 4, l15 = lane & 15;
  const int h64 = h * 64;
  const size_t row_base = (size_t)b * NTOK + (size_t)blk * BLKSZ;
  const f32x4 zero4 = {0.f, 0.f, 0.f, 0.f};

  {
    const u16x8 zero8 = {0, 0, 0, 0, 0, 0, 0, 0};
    for (int c = tid; c < 144 * 8; c += 256) {
      int row = c >> 3, cc = c & 7;
      u16x8 val = zero8;
      if (row < BLKSZ)
        val = *(const u16x8*)(k + (row_base + row) * DIMSZ + h64 + cc * 8);
      *(u16x8*)&sKV[row * 64 + cc * 8] = val;
    }
  }
  __syncthreads();

  // phase 1: S = 0.125 * Q K^T
  {
    int cur_mt = -1;
    bf16x8 qf0, qf1;
    for (int t = w; t < 81; t += 4) {
      int mt = t / 9, nt = t - mt * 9;
      if (mt != cur_mt) {
        cur_mt = mt;
        int qrow = mt * 16 + l15;
        if (qrow > 128) qrow = 128;
        const u16* qp = q + (row_base + qrow) * DIMSZ + h64;
        qf0 = *(const bf16x8*)(qp + qd * 8);
        qf1 = *(const bf16x8*)(qp + 32 + qd * 8);
      }
      bf16x8 kf0 = *(const bf16x8*)&sKV[(nt * 16 + l15) * 64 + qd * 8];
      bf16x8 kf1 = *(const bf16x8*)&sKV[(nt * 16 + l15) * 64 + 32 + qd * 8];
      f32x4 c = zero4;
      c = MFMA(qf0, kf0, c, 0, 0, 0);
      c = MFMA(qf1, kf1, c, 0, 0, 0);
      int r0 = mt * 16 + qd * 4, col = nt * 16 + l15;
#pragma unroll
      for (int r = 0; r < 4; ++r)
        sS[(r0 + r) * 144 + col] = f2bf(c[r] * 0.125f);
    }
  }
  __syncthreads();

  // V^T into sKV
  for (int c = tid; c < BLKSZ * 8; c += 256) {
    int row = c >> 3, cc = c & 7;
    u16x8 val = *(const u16x8*)(v + (row_base + row) * DIMSZ + h64 + cc * 8);
#pragma unroll
    for (int jj = 0; jj < 8; ++jj)
      sKV[(cc * 8 + jj) * 144 + row] = val[jj];
  }

  // softmax over 129 keys
  for (int row = w; row < BLKSZ; row += 4) {
    float x1 = bf2f(sS[row * 144 + lane]);
    float x2 = bf2f(sS[row * 144 + 64 + lane]);
    float x3 = (lane == 0) ? bf2f(sS[row * 144 + 128]) : -3.0e38f;
    float m = fmaxf(fmaxf(x1, x2), x3);
    for (int t = 1; t < 64; t <<= 1) m = fmaxf(m, __shfl_xor(m, t));
    float e1 = __expf(x1 - m), e2 = __expf(x2 - m);
    float e3 = (lane == 0) ? __expf(x3 - m) : 0.f;
    float s = e1 + e2 + e3;
    for (int t = 1; t < 64; t <<= 1) s += __shfl_xor(s, t);
    float inv = 1.f / s;
    sS[row * 144 + lane] = f2bf(e1 * inv);
    sS[row * 144 + 64 + lane] = f2bf(e2 * inv);
    if (lane == 0) sS[row * 144 + 128] = f2bf(e3 * inv);
  }
  __syncthreads();

  // phase 3: out = P V
  for (int t = w; t < 36; t += 4) {
    int mt = t >> 2, nt = t & 3;
    f32x4 c = zero4;
#pragma unroll
    for (int kk = 0; kk < 128; kk += 32) {
      bf16x8 pf = *(const bf16x8*)&sS[(mt * 16 + l15) * 144 + kk + qd * 8];
      bf16x8 vf = *(const bf16x8*)&sKV[(nt * 16 + l15) * 144 + kk + qd * 8];
      c = MFMA(pf, vf, c, 0, 0, 0);
    }
    int dv = nt * 16 + l15;
    float v128 = bf2f(sKV[dv * 144 + 128]);
    int r0 = mt * 16 + qd * 4;
#pragma unroll
    for (int r = 0; r < 4; ++r) {
      int row = r0 + r;
      if (row < BLKSZ) {
        float p128 = bf2f(sS[row * 144 + 128]);
        float val = c[r] + p128 * v128;
        if (row == 0)
          val += g[(((size_t)b * NBLK + blk) * HEADS + h) * 64 + dv];
        ao[(row_base + row) * DIMSZ + h64 + dv] = f2bf(val);
      }
    }
  }
}

// ---------------------------------------------------------------------------
extern "C" void kernel_launch(void* const* d_in, const int* in_sizes, int n_in,
                              void* d_out, int out_size, void* d_ws, size_t ws_size,
                              hipStream_t stream) {
  // Inputs f32; OUTPUT f32 (round-8 verified).
  const float* x  = (const float*)d_in[0];
  const float* Wq = (const float*)d_in[1];
  const float* Wk = (const float*)d_in[2];
  const float* Wv = (const float*)d_in[3];
  const float* Wo = (const float*)d_in[4];
  const float* bo = (const float*)d_in[5];
  float* out = (float*)d_out;

  // Scratch:
  //   d_out (67.6 MB f32) during attention: [v bf16 33.8 MB][k bf16 33.8 MB]
  //     (final GEMM rewrites all of d_out, stream-ordered after last k/v read)
  //   d_ws (68.6 MB used, <= round-4-proven 75.7 MB):
  //     [0,1MB) g | [1MB,+33.8) qb (ao in-place) | [+33.8) x16
  char* ws = (char*)d_ws;
  const size_t xb = (size_t)MROWS * DIMSZ * sizeof(u16);   // 33.8 MB
  float* gb  = (float*)ws;
  u16*   qb  = (u16*)(ws + (1u << 20));
  u16*   x16 = (u16*)(ws + (1u << 20) + xb);
  u16*   vb  = (u16*)d_out;
  u16*   kb  = (u16*)d_out + (size_t)MROWS * DIMSZ;

  const int nx = MROWS * DIMSZ;
  cast_f32_bf16<<<nx / 1024, 256, 0, stream>>>(x, x16, nx);

  dim3 ggrid(MROWS / 128, DIMSZ / 128);   // (129, 8)
  gemm_bt<false, true, false><<<ggrid, 256, 0, stream>>>(x16, Wq, qb, nullptr, MROWS, DIMSZ, DIMSZ);
  gemm_bt<false, true, false><<<ggrid, 256, 0, stream>>>(x16, Wk, kb, nullptr, MROWS, DIMSZ, DIMSZ);
  gemm_bt<false, true, false><<<ggrid, 256, 0, stream>>>(x16, Wv, vb, nullptr, MROWS, DIMSZ, DIMSZ);
  global_attn<<<dim3(BATCH * HEADS), 64, 0, stream>>>(qb, kb, vb, gb);
  block_attn<<<dim3(BATCH, NBLK, HEADS), 256, 0, stream>>>(qb, kb, vb, gb, qb);
  gemm_bt<false, true, true><<<ggrid, 256, 0, stream>>>(qb, Wo, out, bo, MROWS, DIMSZ, DIMSZ);
}

// Round 10
// 519.957 us; speedup vs baseline: 15.4703x; 1.3711x over previous
//
#include <hip/hip_runtime.h>

typedef unsigned short u16;
typedef __attribute__((ext_vector_type(8))) __bf16 bf16x8;
typedef __attribute__((ext_vector_type(4))) float f32x4;
typedef __attribute__((ext_vector_type(8))) u16 u16x8;
typedef __attribute__((ext_vector_type(4))) u16 u16x4;

#define DIMSZ 1024
#define HEADS 16
#define BLKSZ 129
#define NBLK 32
#define NTOK (BLKSZ * NBLK)      // 4128
#define BATCH 4
#define MROWS (BATCH * NTOK)     // 16512

#define MFMA __builtin_amdgcn_mfma_f32_16x16x32_bf16

#define SSTR 152   // S/P LDS row stride (bf16): 2-way bank alias only (free)
#define KSTR 72    // K tile LDS row stride

__device__ __forceinline__ float bf2f(u16 u) {
  return __uint_as_float(((unsigned)u) << 16);
}
__device__ __forceinline__ u16 f2bf(float f) {
  unsigned u = __float_as_uint(f);
  u += 0x7FFFu + ((u >> 16) & 1u);   // round-to-nearest-even
  return (u16)(u >> 16);
}

// async global->LDS, 16B/lane; LDS dest = wave-uniform base + lane*16 (m97)
#define GLD16(ldsp, gp) __builtin_amdgcn_global_load_lds( \
    (const __attribute__((address_space(1))) void*)(gp),   \
    (__attribute__((address_space(3))) void*)(ldsp), 16, 0, 0)

// ---------------------------------------------------------------------------
// f32 -> bf16 cast, 4 elems/thread. n multiple of 1024.
// ---------------------------------------------------------------------------
__global__ __launch_bounds__(256) void cast_f32_bf16(
    const float* __restrict__ in, u16* __restrict__ out, int n)
{
  int i = (blockIdx.x * 256 + threadIdx.x) * 4;
  if (i < n) {
    float4 f = *(const float4*)(in + i);
    u16x4 o = { f2bf(f.x), f2bf(f.y), f2bf(f.z), f2bf(f.w) };
    *(u16x4*)(out + i) = o;
  }
}

// Stage one 128x64 bf16 tile into LDS via global_load_lds width-16.
__device__ __forceinline__ void stage16(u16* dst, const u16* src,
                                        int row0, int K, int k0, int tid) {
#pragma unroll
  for (int i = 0; i < 4; ++i) {
    int off = i * 4096 + tid * 16;     // byte offset in 16 KB tile
    int row = off >> 7;                // 128 B per row (64 bf16)
    int col = (off & 127) >> 1;
    GLD16((char*)dst + off, src + (size_t)(row0 + row) * K + k0 + col);
  }
}

// m97 GEMM mainloop: 128x128 tile, BK=64, 4 waves x 4x4 acc, both ops GLD16.
__device__ __forceinline__ void gemm_core(
    const u16* __restrict__ A, const u16* __restrict__ B,
    int m0, int n0, int K, int tid, u16* sA, u16* sB, f32x4 (*acc)[4])
{
  const int lane = tid & 63;
  const int wid  = tid >> 6;
  const int qd   = lane >> 4;
  const int l15  = lane & 15;
  const int wm = (wid >> 1) * 64;
  const int wn = (wid & 1) * 64;

  for (int k0 = 0; k0 < K; k0 += 64) {
    stage16(sA, A, m0, K, k0, tid);
    stage16(sB, B, n0, K, k0, tid);
    __builtin_amdgcn_s_waitcnt(0);     // drain global_load_lds
    __syncthreads();

#pragma unroll
    for (int kk = 0; kk < 64; kk += 32) {
      bf16x8 af[4], bv[4];
#pragma unroll
      for (int mi = 0; mi < 4; ++mi)
        af[mi] = *(const bf16x8*)&sA[(wm + mi * 16 + l15) * 64 + kk + qd * 8];
#pragma unroll
      for (int ni = 0; ni < 4; ++ni)
        bv[ni] = *(const bf16x8*)&sB[(wn + ni * 16 + l15) * 64 + kk + qd * 8];
#pragma unroll
      for (int mi = 0; mi < 4; ++mi)
#pragma unroll
        for (int ni = 0; ni < 4; ++ni)
          acc[mi][ni] = MFMA(af[mi], bv[ni], acc[mi][ni], 0, 0, 0);
    }
    __syncthreads();
  }
}

// ---------------------------------------------------------------------------
// Fused QKV projection: A=x16 [16512][1024], B=Wqkv16 [3072][1024].
// blockIdx.y 0..23 -> q (0..7), k (8..15), v (16..23); bf16 out, stride 1024.
// ---------------------------------------------------------------------------
__global__ __launch_bounds__(256) void gemm_qkv(
    const u16* __restrict__ A, const u16* __restrict__ B,
    u16* __restrict__ Cq, u16* __restrict__ Ck, u16* __restrict__ Cv)
{
  __shared__ u16 sA[128 * 64];
  __shared__ u16 sB[128 * 64];
  const int tid = threadIdx.x;
  f32x4 acc[4][4];
  for (int mi = 0; mi < 4; ++mi)
    for (int ni = 0; ni < 4; ++ni)
      acc[mi][ni] = (f32x4){0.f, 0.f, 0.f, 0.f};

  const int m0 = blockIdx.x * 128;
  const int nb = blockIdx.y;
  gemm_core(A, B, m0, nb * 128, DIMSZ, tid, sA, sB, acc);

  u16* C = nb < 8 ? Cq : (nb < 16 ? Ck : Cv);
  const int n0 = (nb & 7) * 128;
  const int lane = tid & 63, wid = tid >> 6;
  const int qd = lane >> 4, l15 = lane & 15;
  const int wm = (wid >> 1) * 64, wn = (wid & 1) * 64;
#pragma unroll
  for (int mi = 0; mi < 4; ++mi)
#pragma unroll
    for (int ni = 0; ni < 4; ++ni) {
      int row0 = m0 + wm + mi * 16 + qd * 4;
      int col  = n0 + wn + ni * 16 + l15;
#pragma unroll
      for (int r = 0; r < 4; ++r)
        C[(size_t)(row0 + r) * DIMSZ + col] = f2bf(acc[mi][ni][r]);
    }
}

// ---------------------------------------------------------------------------
// Output projection: A=ao bf16, B=Wo16 bf16, C=f32 d_out, +bias.
// ---------------------------------------------------------------------------
__global__ __launch_bounds__(256) void gemm_out(
    const u16* __restrict__ A, const u16* __restrict__ B,
    float* __restrict__ C, const float* __restrict__ bias)
{
  __shared__ u16 sA[128 * 64];
  __shared__ u16 sB[128 * 64];
  const int tid = threadIdx.x;
  f32x4 acc[4][4];
  for (int mi = 0; mi < 4; ++mi)
    for (int ni = 0; ni < 4; ++ni)
      acc[mi][ni] = (f32x4){0.f, 0.f, 0.f, 0.f};

  const int m0 = blockIdx.x * 128;
  const int n0 = blockIdx.y * 128;
  gemm_core(A, B, m0, n0, DIMSZ, tid, sA, sB, acc);

  const int lane = tid & 63, wid = tid >> 6;
  const int qd = lane >> 4, l15 = lane & 15;
  const int wm = (wid >> 1) * 64, wn = (wid & 1) * 64;
#pragma unroll
  for (int mi = 0; mi < 4; ++mi)
#pragma unroll
    for (int ni = 0; ni < 4; ++ni) {
      int row0 = m0 + wm + mi * 16 + qd * 4;
      int col  = n0 + wn + ni * 16 + l15;
      float badd = bias[col];
#pragma unroll
      for (int r = 0; r < 4; ++r)
        C[(size_t)(row0 + r) * DIMSZ + col] = acc[mi][ni][r] + badd;
    }
}

// ---------------------------------------------------------------------------
// Global attention among the 32 block-leader tokens, per (b,h). One wave/WG.
// ---------------------------------------------------------------------------
__global__ __launch_bounds__(64) void global_attn(
    const u16* __restrict__ q, const u16* __restrict__ k,
    const u16* __restrict__ v, float* __restrict__ g)
{
  __shared__ float sQ[NBLK * 64];
  __shared__ float sKT[64 * NBLK];
  __shared__ float sV[NBLK * 64];
  __shared__ float sp[NBLK];
  const int b = blockIdx.x >> 4, h = blockIdx.x & 15;
  const int lane = threadIdx.x;

  for (int idx = lane; idx < NBLK * 64; idx += 64) {
    int j = idx >> 6, d = idx & 63;
    size_t off = ((size_t)(b * NTOK + j * BLKSZ)) * DIMSZ + h * 64 + d;
    sQ[idx] = bf2f(q[off]);
    sKT[d * NBLK + j] = bf2f(k[off]);
    sV[idx] = bf2f(v[off]);
  }
  __syncthreads();

  for (int i = 0; i < NBLK; ++i) {
    float s = -3.0e38f;
    if (lane < 32) {
      float acc = 0.f;
      for (int d = 0; d < 64; ++d) acc += sQ[i * 64 + d] * sKT[d * NBLK + lane];
      s = acc * 0.125f;
    }
    float m = s;
    for (int t = 1; t < 64; t <<= 1) m = fmaxf(m, __shfl_xor(m, t));
    float e = (lane < 32) ? __expf(s - m) : 0.f;
    float sum = e;
    for (int t = 1; t < 64; t <<= 1) sum += __shfl_xor(sum, t);
    if (lane < 32) sp[lane] = e / sum;
    __syncthreads();
    float acc = 0.f;
    for (int jj = 0; jj < NBLK; ++jj) acc += sp[jj] * sV[jj * 64 + lane];
    g[(((size_t)b * NBLK + i) * HEADS + h) * 64 + lane] = acc;
    __syncthreads();
  }
}

// ---------------------------------------------------------------------------
// MFMA block-local attention, 512 threads (8 waves) per (b, blk, h).
// LDS: sS 144xSSTR (43.8 KB), sKV union (20.7 KB) -> 64.5 KB, 2 WG/CU,
// 16 waves/CU. Strides 152/72 cut 4-16-way LDS bank aliasing to <=2-way.
// Writes ao IN PLACE over q (disjoint WG slices; q reads precede stores).
// ---------------------------------------------------------------------------
__global__ __launch_bounds__(512) void block_attn(
    const u16* q, const u16* __restrict__ k,
    const u16* __restrict__ v, const float* __restrict__ g,
    u16* ao)
{
  __shared__ u16 sS[144 * SSTR];    // scores then P (bf16)
  __shared__ u16 sKV[144 * KSTR];   // phase1: K [key][d] (KSTR); phase3: V^T [dv][key] (SSTR)
  const int b = blockIdx.x, blk = blockIdx.y, h = blockIdx.z;
  const int tid = threadIdx.x, lane = tid & 63, w = tid >> 6;
  const int qd = lane >> 4, l15 = lane & 15;
  const int h64 = h * 64;
  const size_t row_base = (size_t)b * NTOK + (size_t)blk * BLKSZ;
  const f32x4 zero4 = {0.f, 0.f, 0.f, 0.f};

  // ---- K tile [key][d], rows 129..143 zeroed ----
  {
    const u16x8 zero8 = {0, 0, 0, 0, 0, 0, 0, 0};
    for (int c = tid; c < 144 * 8; c += 512) {
      int row = c >> 3, cc = c & 7;
      u16x8 val = zero8;
      if (row < BLKSZ)
        val = *(const u16x8*)(k + (row_base + row) * DIMSZ + h64 + cc * 8);
      *(u16x8*)&sKV[row * KSTR + cc * 8] = val;
    }
  }
  __syncthreads();

  // ---- phase 1: S = 0.125 * Q K^T (81 tiles over 8 waves) ----
  for (int t = w; t < 81; t += 8) {
    int mt = t / 9, nt = t - mt * 9;
    int qrow = mt * 16 + l15;
    if (qrow > 128) qrow = 128;        // clamp: keep reads in-bounds
    const u16* qp = q + (row_base + qrow) * DIMSZ + h64;
    bf16x8 qf0 = *(const bf16x8*)(qp + qd * 8);
    bf16x8 qf1 = *(const bf16x8*)(qp + 32 + qd * 8);
    bf16x8 kf0 = *(const bf16x8*)&sKV[(nt * 16 + l15) * KSTR + qd * 8];
    bf16x8 kf1 = *(const bf16x8*)&sKV[(nt * 16 + l15) * KSTR + 32 + qd * 8];
    f32x4 c = zero4;
    c = MFMA(qf0, kf0, c, 0, 0, 0);
    c = MFMA(qf1, kf1, c, 0, 0, 0);
    int r0 = mt * 16 + qd * 4, col = nt * 16 + l15;
#pragma unroll
    for (int r = 0; r < 4; ++r)
      sS[(r0 + r) * SSTR + col] = f2bf(c[r] * 0.125f);
  }
  __syncthreads();

  // ---- V^T [dv][key] stride SSTR into sKV (K tile dead) ----
  for (int c = tid; c < BLKSZ * 8; c += 512) {
    int row = c >> 3, cc = c & 7;      // row = key index
    u16x8 val = *(const u16x8*)(v + (row_base + row) * DIMSZ + h64 + cc * 8);
#pragma unroll
    for (int jj = 0; jj < 8; ++jj)
      sKV[(cc * 8 + jj) * SSTR + row] = val[jj];
  }

  // ---- softmax over 129 keys (rows over 8 waves) ----
  for (int row = w; row < BLKSZ; row += 8) {
    float x1 = bf2f(sS[row * SSTR + lane]);
    float x2 = bf2f(sS[row * SSTR + 64 + lane]);
    float x3 = (lane == 0) ? bf2f(sS[row * SSTR + 128]) : -3.0e38f;
    float m = fmaxf(fmaxf(x1, x2), x3);
    for (int t = 1; t < 64; t <<= 1) m = fmaxf(m, __shfl_xor(m, t));
    float e1 = __expf(x1 - m), e2 = __expf(x2 - m);
    float e3 = (lane == 0) ? __expf(x3 - m) : 0.f;
    float s = e1 + e2 + e3;
    for (int t = 1; t < 64; t <<= 1) s += __shfl_xor(s, t);
    float inv = 1.f / s;
    sS[row * SSTR + lane] = f2bf(e1 * inv);
    sS[row * SSTR + 64 + lane] = f2bf(e2 * inv);
    if (lane == 0) sS[row * SSTR + 128] = f2bf(e3 * inv);
  }
  __syncthreads();

  // ---- phase 3: out = P V (keys 0..127 MFMA + rank-1 key 128) ----
  for (int t = w; t < 36; t += 8) {
    int mt = t >> 2, nt = t & 3;
    f32x4 c = zero4;
#pragma unroll
    for (int kk = 0; kk < 128; kk += 32) {
      bf16x8 pf = *(const bf16x8*)&sS[(mt * 16 + l15) * SSTR + kk + qd * 8];
      bf16x8 vf = *(const bf16x8*)&sKV[(nt * 16 + l15) * SSTR + kk + qd * 8];
      c = MFMA(pf, vf, c, 0, 0, 0);
    }
    int dv = nt * 16 + l15;
    float v128 = bf2f(sKV[dv * SSTR + 128]);
    int r0 = mt * 16 + qd * 4;
#pragma unroll
    for (int r = 0; r < 4; ++r) {
      int row = r0 + r;
      if (row < BLKSZ) {
        float p128 = bf2f(sS[row * SSTR + 128]);
        float val = c[r] + p128 * v128;
        if (row == 0)
          val += g[(((size_t)b * NBLK + blk) * HEADS + h) * 64 + dv];
        ao[(row_base + row) * DIMSZ + h64 + dv] = f2bf(val);
      }
    }
  }
}

// ---------------------------------------------------------------------------
extern "C" void kernel_launch(void* const* d_in, const int* in_sizes, int n_in,
                              void* d_out, int out_size, void* d_ws, size_t ws_size,
                              hipStream_t stream) {
  // Inputs f32; OUTPUT f32 (round-8 verified).
  const float* x  = (const float*)d_in[0];
  const float* Wq = (const float*)d_in[1];
  const float* Wk = (const float*)d_in[2];
  const float* Wv = (const float*)d_in[3];
  const float* Wo = (const float*)d_in[4];
  const float* bo = (const float*)d_in[5];
  float* out = (float*)d_out;

  // Scratch:
  //   d_out (67.6 MB) during attention: [k bf16 33.8][v bf16 33.8]
  //   d_ws (74.6 MB peak <= round-4-proven 75.7):
  //     [0,1MB) g | [1,+33.8) qb (ao in-place) | [+33.8) x16 | [+6MB) Wqkv16
  //   Wo16 reuses the x16 region (cast launched after gemm_qkv, stream-ordered).
  char* ws = (char*)d_ws;
  const size_t xb = (size_t)MROWS * DIMSZ * sizeof(u16);   // 33.8 MB
  float* gb     = (float*)ws;
  u16*   qb     = (u16*)(ws + (1u << 20));
  u16*   x16    = (u16*)(ws + (1u << 20) + xb);
  u16*   Wqkv16 = (u16*)(ws + (1u << 20) + 2 * xb);
  u16*   Wo16   = x16;                     // reused after gemm_qkv
  u16*   kb     = (u16*)d_out;
  u16*   vb     = (u16*)d_out + (size_t)MROWS * DIMSZ;

  const int nx = MROWS * DIMSZ;
  const int nw = DIMSZ * DIMSZ;
  cast_f32_bf16<<<nx / 1024, 256, 0, stream>>>(x,  x16, nx);
  cast_f32_bf16<<<nw / 1024, 256, 0, stream>>>(Wq, Wqkv16,          nw);
  cast_f32_bf16<<<nw / 1024, 256, 0, stream>>>(Wk, Wqkv16 + nw,     nw);
  cast_f32_bf16<<<nw / 1024, 256, 0, stream>>>(Wv, Wqkv16 + 2 * nw, nw);

  gemm_qkv<<<dim3(MROWS / 128, 24), 256, 0, stream>>>(x16, Wqkv16, qb, kb, vb);

  cast_f32_bf16<<<nw / 1024, 256, 0, stream>>>(Wo, Wo16, nw);   // after qkv: x16 dead

  global_attn<<<dim3(BATCH * HEADS), 64, 0, stream>>>(qb, kb, vb, gb);
  block_attn<<<dim3(BATCH, NBLK, HEADS), 512, 0, stream>>>(qb, kb, vb, gb, qb);
  gemm_out<<<dim3(MROWS / 128, DIMSZ / 128), 256, 0, stream>>>(qb, Wo16, out, bo);
}